// Round 15
// baseline (753.042 us; speedup 1.0000x reference)
//
#include <hip/hip_runtime.h>

#define TT 4096      // B*S tokens
#define SS 2048
#define DD 1024
#define NH 16
#define NE 8
#define DFFC 4096

typedef _Float16 h8  __attribute__((ext_vector_type(8)));
typedef _Float16 h4v __attribute__((ext_vector_type(4)));
typedef float    f4  __attribute__((ext_vector_type(4)));

typedef __attribute__((address_space(3))) void lds_void;
typedef __attribute__((address_space(1))) const void gbl_void;

__device__ __forceinline__ f4 mfma16(h8 a, h8 b, f4 c){
  return __builtin_amdgcn_mfma_f32_16x16x32_f16(a, b, c, 0, 0, 0);
}
__device__ __forceinline__ void fsplit(float x, _Float16& hi, _Float16& lo){
  _Float16 h = (_Float16)x; hi = h; lo = (_Float16)(x - (float)h);
}
// async global->LDS, 16B per lane. LDS dest must be linear (base + lane*16).
__device__ __forceinline__ void gll16(const void* g, void* l){
  __builtin_amdgcn_global_load_lds((gbl_void*)g, (lds_void*)l, 16, 0, 0);
}

// ---------------- transpose+convert: in f32 [K][N] -> out f16 [N][K] (split or single)
template<int SPLIT>
__global__ __launch_bounds__(256) void conv_t(
    const float* __restrict__ in, _Float16* __restrict__ oh, _Float16* __restrict__ ol,
    int K, int N)
{
  __shared__ float tile[64][65];
  const int n0 = blockIdx.x*64, k0 = blockIdx.y*64;
  const int tid = threadIdx.x;
  const float* inp = in + (size_t)blockIdx.z*K*N;
  #pragma unroll
  for (int p=0;p<4;++p){
    int row = p*16 + (tid>>4), col4 = (tid&15)*4;
    *(f4*)&tile[row][col4] = *(const f4*)(inp + (size_t)(k0+row)*N + n0 + col4);
  }
  __syncthreads();
  const size_t ob = (size_t)blockIdx.z*K*N;
  #pragma unroll
  for (int p=0;p<2;++p){
    int n = p*32 + (tid>>3), k8 = (tid&7)*8;
    h8 vh, vl;
    #pragma unroll
    for (int j=0;j<8;++j){
      float v = tile[k8+j][n];
      if constexpr (SPLIT){ _Float16 hi,lo; fsplit(v,hi,lo); vh[j]=hi; vl[j]=lo; }
      else vh[j] = (_Float16)v;
    }
    size_t o = ob + (size_t)(n0+n)*K + k0 + k8;
    *(h8*)(oh + o) = vh;
    if constexpr (SPLIT) *(h8*)(ol + o) = vl;
  }
}

// ---------------- LayerNorm (LN1): fp32 in -> split f16 planes
__global__ __launch_bounds__(256) void ln_kernel(
    const float* __restrict__ in, const float* __restrict__ g, const float* __restrict__ b,
    _Float16* __restrict__ outHi, _Float16* __restrict__ outLo)
{
  const int t = blockIdx.x, tid = threadIdx.x;
  f4 v = ((const f4*)(in + (size_t)t*DD))[tid];
  float s = v.x+v.y+v.z+v.w;
  float q = v.x*v.x+v.y*v.y+v.z*v.z+v.w*v.w;
  #pragma unroll
  for (int off=32; off; off>>=1){ s += __shfl_xor(s,off); q += __shfl_xor(q,off); }
  __shared__ float red[8];
  int wid = tid>>6, lane = tid&63;
  if (lane==0){ red[wid]=s; red[4+wid]=q; }
  __syncthreads();
  s = red[0]+red[1]+red[2]+red[3];
  q = red[4]+red[5]+red[6]+red[7];
  float mean = s * (1.0f/DD);
  float var  = q * (1.0f/DD) - mean*mean;
  float vv = var + 1e-5f;
  float r = rsqrtf(vv);
  r = r * (1.5f - 0.5f*vv*r*r);
  f4 gv = ((const f4*)g)[tid], bv = ((const f4*)b)[tid];
  #pragma unroll
  for (int j=0;j<4;++j){
    float y = (v[j]-mean)*r*gv[j] + bv[j];
    size_t o = (size_t)t*DD + tid*4 + j;
    _Float16 hi,lo; fsplit(y,hi,lo); outHi[o]=hi; outLo[o]=lo;
  }
}

// ---------------- split-precision GEMM (3-term), single-buffer 2-barrier loop (m97 style)
template<int MODE>
__global__ __launch_bounds__(256,3) void gemm_split3(
    const _Float16* __restrict__ Ah, const _Float16* __restrict__ Al,
    const _Float16* __restrict__ Bh, const _Float16* __restrict__ Bl,
    const float* __restrict__ bias,
    _Float16* __restrict__ Chi, _Float16* __restrict__ Clo,
    float* __restrict__ Cf, const float* __restrict__ resid,
    int N, int K, int GM)
{
  __shared__ __align__(16) char smem[32768];   // A 16K + B 16K, single buffer
  const int tid = threadIdx.x, lane = tid&63, wid = tid>>6;
  const int l15 = lane&15, l4 = lane>>4;
  const int bid = blockIdx.x;
  const int c = bid & 7, rr = bid >> 3, mpx = GM >> 3;
  const int tm = (c*mpx + (rr % mpx))*128, tn = (rr / mpx)*128;

  const _Float16* sA[4]; const _Float16* sB[4];
  #pragma unroll
  for (int i=0;i<4;++i){
    int row = i*32 + (tid>>3);
    int s = (tid&7) ^ (row&7);
    int plane = s>>2, koff = (s&3)*8;
    sA[i] = (plane ? Al : Ah) + (size_t)(tm+row)*K + koff;
    sB[i] = (plane ? Bl : Bh) + (size_t)(tn+row)*K + koff;
  }
  int offAh[4], offAl[4], offBh[4], offBl[4];
  #pragma unroll
  for (int m=0;m<4;++m){
    int rowA = (wid>>1)*64 + m*16 + l15;
    offAh[m] = rowA*64 + ((l4 ^ (rowA&7))<<3);
    offAl[m] = rowA*64 + (((4|l4) ^ (rowA&7))<<3);
    int rowB = (wid&1)*64 + m*16 + l15;
    offBh[m] = rowB*64 + ((l4 ^ (rowB&7))<<3);
    offBl[m] = rowB*64 + (((4|l4) ^ (rowB&7))<<3);
  }
  f4 acc[4][4] = {};
  const _Float16* As = (const _Float16*)(smem);
  const _Float16* Bs = (const _Float16*)(smem + 16384);
  for (int k0=0; k0<K; k0+=32){
    #pragma unroll
    for (int i=0;i<4;++i){
      int L = i*4096 + tid*16;
      gll16(sA[i]+k0, smem + L);
      gll16(sB[i]+k0, smem + 16384 + L);
    }
    __syncthreads();
    h8 ah[4], al[4], bh4[4], bl4[4];
    #pragma unroll
    for (int m=0;m<4;++m){ ah[m] = *(const h8*)&As[offAh[m]]; al[m] = *(const h8*)&As[offAl[m]]; }
    #pragma unroll
    for (int n=0;n<4;++n){ bh4[n] = *(const h8*)&Bs[offBh[n]]; bl4[n] = *(const h8*)&Bs[offBl[n]]; }
    #pragma unroll
    for (int n=0;n<4;++n)
      #pragma unroll
      for (int m=0;m<4;++m){
        acc[m][n] = mfma16(ah[m], bh4[n], acc[m][n]);
        acc[m][n] = mfma16(ah[m], bl4[n], acc[m][n]);
        acc[m][n] = mfma16(al[m], bh4[n], acc[m][n]);
      }
    __syncthreads();
  }
  const int wm = (wid>>1)*64, wn = (wid&1)*64;
  #pragma unroll
  for (int n=0;n<4;++n){
    int col = tn + wn + n*16 + l15;
    float bv = bias[col];
    #pragma unroll
    for (int m=0;m<4;++m)
      #pragma unroll
      for (int r=0;r<4;++r){
        int rowg = tm + wm + m*16 + l4*4 + r;
        float vv = acc[m][n][r] + bv;
        size_t co = (size_t)rowg*N + col;
        if constexpr (MODE==0){ _Float16 hi,lo; fsplit(vv,hi,lo); Chi[co]=hi; Clo[co]=lo; }
        else { Cf[co] = vv + resid[co]; }
      }
  }
}

// ---------------- V pre-transpose: qkv planes -> vt [bh][64 d][2048 tokens]
__global__ __launch_bounds__(256) void vt_kernel(
    const _Float16* __restrict__ qkvH, const _Float16* __restrict__ qkvL,
    _Float16* __restrict__ vtH, _Float16* __restrict__ vtL)
{
  __shared__ _Float16 TH[64*72], TL[64*72];
  const int tid = threadIdx.x;
  const int tt = blockIdx.x*64;
  const int bh = blockIdx.y;
  const int b = bh>>4, h = bh&15;
  const size_t t0 = (size_t)b*SS;
  #pragma unroll
  for (int p=0;p<2;++p){
    int t = p*32 + (tid>>3), d0 = (tid&7)*8;
    size_t g = (t0 + tt + t)*(size_t)3072 + 2048 + h*64 + d0;
    h8 vh = *(const h8*)(qkvH+g), vl = *(const h8*)(qkvL+g);
    int cp = ((t>>3) ^ (tid&7)) & 7;        // swizzled t-chunk
    int base = cp*8 + (t&7);
    #pragma unroll
    for (int j=0;j<8;++j){ TH[(d0+j)*72 + base] = vh[j]; TL[(d0+j)*72 + base] = vl[j]; }
  }
  __syncthreads();
  int d = tid>>2, seg = tid&3;
  size_t ob = ((size_t)bh*64 + d)*2048 + tt;
  #pragma unroll
  for (int jj=0;jj<2;++jj){
    int cch = jj*4 + seg, cp = (cch ^ (d>>3)) & 7;
    h8 vh = *(const h8*)&TH[d*72 + cp*8];
    h8 vl = *(const h8*)&TL[d*72 + cp*8];
    *(h8*)(vtH + ob + cch*8) = vh;
    *(h8*)(vtL + ob + cch*8) = vl;
  }
}

// ---------------- flash attention, split-f16, swapped QK^T + fixed-shift softmax
__global__ __launch_bounds__(256,3) void attn_kernel(
    const _Float16* __restrict__ qkvH, const _Float16* __restrict__ qkvL,
    const _Float16* __restrict__ vtH, const _Float16* __restrict__ vtL,
    _Float16* __restrict__ oH, _Float16* __restrict__ oL)
{
  __shared__ __align__(16) _Float16 KsH[64*64], KsL[64*64], VsH[64*64], VsL[64*64];
  __shared__ __align__(16) _Float16 Plds[10240];  // 4 waves x (32q x 80B hi + 32q x 80B lo)
  const int tid = threadIdx.x, lane = tid & 63, wid = tid >> 6;
  const int l15 = lane & 15, l4 = lane >> 4;
  const int qt = blockIdx.x, bh = blockIdx.y;
  const int b = bh >> 4, h = bh & 15;
  const size_t t0 = (size_t)b * SS;
  const int qbase = qt*128 + wid*32;

  const int srow = tid>>3;
  const int ss = (tid&7) ^ (srow&7);
  const _Float16* kH = qkvH + (t0 + srow)*(size_t)3072 + 1024 + h*64 + ss*8;
  const _Float16* kL = qkvL + (t0 + srow)*(size_t)3072 + 1024 + h*64 + ss*8;
  const _Float16* vH = vtH + ((size_t)bh*64 + srow)*2048 + ss*8;
  const _Float16* vL = vtL + ((size_t)bh*64 + srow)*2048 + ss*8;
  const int ldsL0 = tid*16;

  int offF[4][2];
  #pragma unroll
  for (int n=0;n<4;++n)
    #pragma unroll
    for (int ks=0;ks<2;++ks){
      int row = n*16 + l15;
      offF[n][ks] = row*64 + (((ks*4 + l4) ^ (row&7))<<3);
    }
  int pq[2], prb[2];
  #pragma unroll
  for (int m=0;m<2;++m){
    int q = m*16 + l15;
    pq[m]  = wid*5120 + q*80;
    prb[m] = pq[m] + l4*16;
  }

  h8 qh[2][2], ql[2][2];
  #pragma unroll
  for (int m=0;m<2;++m)
    #pragma unroll
    for (int ks=0;ks<2;++ks){
      size_t go = (t0 + qbase + m*16 + l15)*(size_t)3072 + h*64 + ks*32 + l4*8;
      qh[m][ks] = *(const h8*)(qkvH + go);
      ql[m][ks] = *(const h8*)(qkvL + go);
    }

  f4 oacc[2][4] = {};
  float psum[2] = {0.f, 0.f};

  for (int kv=0; kv<SS; kv+=64){
    #pragma unroll
    for (int cc=0; cc<2; ++cc){
      size_t kgo = (size_t)(kv + cc*32)*3072;
      size_t vgo = (size_t)kv + (size_t)cc*32*2048;
      int L = cc*4096 + ldsL0;
      gll16(kH + kgo, (char*)KsH + L);
      gll16(kL + kgo, (char*)KsL + L);
      gll16(vH + vgo, (char*)VsH + L);
      gll16(vL + vgo, (char*)VsL + L);
    }
    __syncthreads();

    #pragma unroll
    for (int half=0; half<2; ++half){
      f4 s[2][2] = {};
      __builtin_amdgcn_s_setprio(1);
      #pragma unroll
      for (int n2=0;n2<2;++n2){
        int nn = half*2 + n2;
        #pragma unroll
        for (int ks=0;ks<2;++ks){
          h8 kh = *(const h8*)&KsH[offF[nn][ks]];
          h8 kl = *(const h8*)&KsL[offF[nn][ks]];
          s[0][n2] = mfma16(kh, qh[0][ks], s[0][n2]);
          s[0][n2] = mfma16(kl, qh[0][ks], s[0][n2]);
          s[0][n2] = mfma16(kh, ql[0][ks], s[0][n2]);
          s[1][n2] = mfma16(kh, qh[1][ks], s[1][n2]);
          s[1][n2] = mfma16(kl, qh[1][ks], s[1][n2]);
          s[1][n2] = mfma16(kh, ql[1][ks], s[1][n2]);
        }
      }
      __builtin_amdgcn_s_setprio(0);
      #pragma unroll
      for (int m=0;m<2;++m){
        #pragma unroll
        for (int n2=0;n2<2;++n2){
          f4 sv = s[m][n2];
          float p0 = __expf(fmaf(sv.x, 0.125f, -8.0f));
          float p1 = __expf(fmaf(sv.y, 0.125f, -8.0f));
          float p2 = __expf(fmaf(sv.z, 0.125f, -8.0f));
          float p3 = __expf(fmaf(sv.w, 0.125f, -8.0f));
          psum[m] += (p0+p1)+(p2+p3);
          h4v hv, lv; _Float16 hh, ll;
          fsplit(p0,hh,ll); hv[0]=hh; lv[0]=ll;
          fsplit(p1,hh,ll); hv[1]=hh; lv[1]=ll;
          fsplit(p2,hh,ll); hv[2]=hh; lv[2]=ll;
          fsplit(p3,hh,ll); hv[3]=hh; lv[3]=ll;
          int wb = pq[m] + n2*32 + l4*8;
          *(h4v*)((char*)Plds + wb) = hv;
          *(h4v*)((char*)Plds + 2560 + wb) = lv;
        }
      }
      __builtin_amdgcn_s_setprio(1);
      h8 paH0 = *(const h8*)((char*)Plds + prb[0]);
      h8 paL0 = *(const h8*)((char*)Plds + 2560 + prb[0]);
      h8 paH1 = *(const h8*)((char*)Plds + prb[1]);
      h8 paL1 = *(const h8*)((char*)Plds + 2560 + prb[1]);
      #pragma unroll
      for (int nd=0;nd<4;++nd){
        h8 vh = *(const h8*)&VsH[offF[nd][half]];
        h8 vl = *(const h8*)&VsL[offF[nd][half]];
        oacc[0][nd] = mfma16(paH0, vh, oacc[0][nd]);
        oacc[0][nd] = mfma16(paH0, vl, oacc[0][nd]);
        oacc[0][nd] = mfma16(paL0, vh, oacc[0][nd]);
        oacc[1][nd] = mfma16(paH1, vh, oacc[1][nd]);
        oacc[1][nd] = mfma16(paH1, vl, oacc[1][nd]);
        oacc[1][nd] = mfma16(paL1, vh, oacc[1][nd]);
      }
      __builtin_amdgcn_s_setprio(0);
    }
    __syncthreads();
  }

  #pragma unroll
  for (int m=0;m<2;++m){
    float ls = psum[m];
    ls += __shfl_xor(ls, 16);
    ls += __shfl_xor(ls, 32);
    #pragma unroll
    for (int r=0;r<4;++r){
      int srcl = l4*4 + r;
      float lq = __uint_as_float(
          (unsigned)__builtin_amdgcn_ds_bpermute(srcl*4, (int)__float_as_uint(ls)));
      float linv = 1.0f / lq;
      #pragma unroll
      for (int nd=0;nd<4;++nd){
        float vv = oacc[m][nd][r] * linv;
        size_t go = (t0 + qbase + m*16 + l4*4 + r)*(size_t)DD + h*64 + nd*16 + l15;
        _Float16 hi, lo; fsplit(vv, hi, lo);
        oH[go] = hi; oL[go] = lo;
      }
    }
  }
}

// ---------------- fused LN2 + gate: x1 fp32 -> h2h f16 plane + top-2 routing.
__global__ __launch_bounds__(256) void gate_kernel(
    const float* __restrict__ x1, const float* __restrict__ g, const float* __restrict__ bb,
    const float* __restrict__ gw, const float* __restrict__ gb,
    _Float16* __restrict__ h2h,
    int* __restrict__ topi, float* __restrict__ topw, int* __restrict__ cnt)
{
  const int t = blockIdx.x*4 + (threadIdx.x>>6), lane = threadIdx.x & 63;
  f4 xv[4];
  float s=0.f, q=0.f;
  #pragma unroll
  for (int i=0;i<4;++i){
    xv[i] = ((const f4*)(x1 + (size_t)t*DD))[lane + i*64];
    #pragma unroll
    for (int j=0;j<4;++j){ s += xv[i][j]; q += xv[i][j]*xv[i][j]; }
  }
  #pragma unroll
  for (int off=32; off; off>>=1){ s += __shfl_xor(s,off); q += __shfl_xor(q,off); }
  float mean = s*(1.f/DD), var = q*(1.f/DD)-mean*mean, vv = var+1e-5f;
  float r = rsqrtf(vv); r = r*(1.5f-0.5f*vv*r*r);
  float acc[8] = {0,0,0,0,0,0,0,0};
  #pragma unroll
  for (int i=0;i<4;++i){
    f4 gv = ((const f4*)g)[lane+i*64], bv = ((const f4*)bb)[lane+i*64];
    h4v hv4;
    #pragma unroll
    for (int j=0;j<4;++j){
      int d = (lane+i*64)*4 + j;
      float hv = (xv[i][j]-mean)*r*gv[j] + bv[j];
      hv4[j] = (_Float16)hv;
      const f4* gp = (const f4*)(gw + (size_t)d*8);
      f4 g0 = gp[0], g1 = gp[1];
      acc[0]+=hv*g0.x; acc[1]+=hv*g0.y; acc[2]+=hv*g0.z; acc[3]+=hv*g0.w;
      acc[4]+=hv*g1.x; acc[5]+=hv*g1.y; acc[6]+=hv*g1.z; acc[7]+=hv*g1.w;
    }
    *(h4v*)(h2h + (size_t)t*DD + (lane+i*64)*4) = hv4;   // fused ln2 f16 output
  }
  #pragma unroll
  for (int e=0;e<8;++e)
    #pragma unroll
    for (int off=32;off;off>>=1) acc[e]+=__shfl_xor(acc[e],off);
  if (lane==0){
    float lg[8];
    #pragma unroll
    for (int e=0;e<8;++e) lg[e]=acc[e]+gb[e];
    int i0=0; float v0=lg[0];
    #pragma unroll
    for (int e=1;e<8;++e) if (lg[e]>v0){ v0=lg[e]; i0=e; }
    int i1=-1; float v1=-1e30f;
    #pragma unroll
    for (int e=0;e<8;++e) if (e!=i0 && lg[e]>v1){ v1=lg[e]; i1=e; }
    float w0 = 1.f/(1.f+__expf(v1-v0));
    topi[2*t]=i0; topi[2*t+1]=i1;
    topw[2*t]=w0; topw[2*t+1]=1.f-w0;
    atomicAdd(&cnt[i0],1); atomicAdd(&cnt[i1],1);
  }
}

__global__ void scan_kernel(const int* __restrict__ cnt, int* __restrict__ offs,
                            int* __restrict__ cursor, int* __restrict__ pref1,
                            int* __restrict__ pref2){
  if (threadIdx.x==0){
    int s=0, t1=0, t2=0;
    for (int e=0;e<8;++e){
      offs[e]=s; s+=cnt[e];
      int mt = (cnt[e]+127)>>7;
      pref1[e]=t1; t1 += mt*(DFFC/128);
      pref2[e]=t2; t2 += mt*(DD/128)*2;   // x2: split-K halves
    }
    offs[8]=s; pref1[8]=t1; pref2[8]=t2;
  }
  if (threadIdx.x<8) cursor[threadIdx.x]=0;
}

__global__ __launch_bounds__(256) void scatter_kernel(
    const int* __restrict__ topi, const int* __restrict__ offs, int* __restrict__ cursor,
    int* __restrict__ tokl, int* __restrict__ posof)
{
  int t = blockIdx.x*256 + threadIdx.x;
  #pragma unroll
  for (int k=0;k<2;++k){
    int e = topi[2*t+k];
    int p = atomicAdd(&cursor[e],1);
    int idx = offs[e]+p;
    tokl[idx]=t; posof[2*t+k]=idx;
  }
}

// ---------------- grouped expert GEMM, f16 x f16, BK=64, T3-min 2-phase dbuf (64KB),
// one drain-barrier per K-step, stage-next issued BEFORE compute. 2 blocks/CU.
template<int GATHER, int KH>
__global__ __launch_bounds__(256,2) void gemm_ffn(
    const _Float16* __restrict__ A, const _Float16* __restrict__ Bw,
    const float* __restrict__ bias, _Float16* __restrict__ C0, _Float16* __restrict__ C1,
    const int* __restrict__ tok, const int* __restrict__ offs,
    const int* __restrict__ pref, int N, int K)
{
  __shared__ __align__(16) char smem[65536];   // 2 bufs x (A 16K + B 16K)
  const int tid = threadIdx.x, lane = tid&63, wid = tid>>6;
  const int l15 = lane&15, l4 = lane>>4;
  const int wm = (wid>>1)*64, wn = (wid&1)*64;
  const int tot = pref[8];
  const int nt = N>>7;
  const int KSEG = K/KH;

  int offA[4][2], offB[4][2];
  #pragma unroll
  for (int m=0;m<4;++m)
    #pragma unroll
    for (int ks=0;ks<2;++ks){
      int rowA = wm + m*16 + l15;
      offA[m][ks] = rowA*64 + (((ks*4+l4) ^ (rowA&7))<<3);
      int rowB = wn + m*16 + l15;
      offB[m][ks] = rowB*64 + (((ks*4+l4) ^ (rowB&7))<<3);
    }

  // XCD-chunked bijective swizzle (gridDim.x % 8 == 0)
  const int cpx = gridDim.x >> 3;
  const int bswz = (blockIdx.x & 7)*cpx + (blockIdx.x >> 3);
  for (int idx = bswz; idx < tot; idx += gridDim.x){
    int e = 0;
    #pragma unroll
    for (int k=1;k<8;++k) if (pref[k] <= idx) e = k;
    const int off = offs[e], Me = offs[e+1]-off;
    const int mt = (Me+127)>>7;
    int local = idx - pref[e];
    int kh = 0;
    if constexpr (KH==2){ int per = mt*nt; kh = (local >= per); local -= kh*per; }
    const int ni = local / mt, mi = local - ni*mt;
    const int tm = mi*128, tn = ni*128;
    const int kb = kh*KSEG;
    const _Float16* Bp = Bw + (size_t)e*N*K + (size_t)tn*K;
    const float* biasp = bias + (size_t)e*N;

    const _Float16* sA[4]; const _Float16* sB[4];
    #pragma unroll
    for (int i=0;i<4;++i){
      int row = i*32 + (tid>>3);
      int s = (tid&7) ^ (row&7);
      int lr = min(tm+row, Me-1);
      size_t ar = GATHER ? (size_t)tok[off+lr] : (size_t)(off+lr);
      sA[i] = A + ar*K + s*8 + kb;
      sB[i] = Bp + (size_t)row*K + s*8 + kb;
    }
    // prologue: stage buf0
    #pragma unroll
    for (int i=0;i<4;++i){
      int L = i*4096 + tid*16;
      gll16(sA[i], smem + L);
      gll16(sB[i], smem + 16384 + L);
    }
    __syncthreads();
    f4 acc[4][4] = {};
    int cur = 0;
    for (int k0=0; k0<KSEG; k0+=64){
      // issue next-tile stage FIRST (into the other buffer)
      if (k0+64 < KSEG){
        int nb = (cur^1)*32768;
        #pragma unroll
        for (int i=0;i<4;++i){
          int L = i*4096 + tid*16;
          gll16(sA[i]+k0+64, smem + nb + L);
          gll16(sB[i]+k0+64, smem + nb + 16384 + L);
        }
      }
      // compute from current buffer (frags consumed immediately, not held across barrier)
      const _Float16* As = (const _Float16*)(smem + cur*32768);
      const _Float16* Bs = (const _Float16*)(smem + cur*32768 + 16384);
      #pragma unroll
      for (int ks=0;ks<2;++ks){
        h8 av[4], bv[4];
        #pragma unroll
        for (int m=0;m<4;++m) av[m] = *(const h8*)&As[offA[m][ks]];
        #pragma unroll
        for (int n=0;n<4;++n) bv[n] = *(const h8*)&Bs[offB[n][ks]];
        #pragma unroll
        for (int n=0;n<4;++n)
          #pragma unroll
          for (int m=0;m<4;++m)
            acc[m][n] = mfma16(av[m], bv[n], acc[m][n]);
      }
      __syncthreads();   // single drain: next-tile loads landed + cur reads done
      cur ^= 1;
    }
    // epilogue: LDS bounce, two 64-col passes, coalesced 16B stores
    _Float16* Cp = (KH==2 && kh==1) ? C1 : C0;
    _Float16* Cs = (_Float16*)smem;
    float bvv[4];
    #pragma unroll
    for (int n=0;n<4;++n) bvv[n] = (KH==2 && kh==1) ? 0.f : biasp[tn + wn + n*16 + l15];
    #pragma unroll
    for (int p=0;p<2;++p){
      if ((wid&1)==p){
        #pragma unroll
        for (int n=0;n<4;++n)
          #pragma unroll
          for (int m=0;m<4;++m)
            #pragma unroll
            for (int r=0;r<4;++r){
              int row = wm + m*16 + l4*4 + r;
              float vv = acc[m][n][r] + bvv[n];
              if constexpr (GATHER) vv = fmaxf(vv, 0.f);
              Cs[row*72 + n*16 + l15] = (_Float16)vv;
            }
      }
      __syncthreads();
      int row = tid>>1, seg = tid&1;
      if (tm+row < Me){
        size_t gb = (size_t)(off+tm+row)*N + tn + p*64 + seg*32;
        #pragma unroll
        for (int j=0;j<4;++j)
          *(h8*)(Cp + gb + j*8) = *(const h8*)&Cs[row*72 + seg*32 + j*8];
      }
      __syncthreads();
    }
  }
}

// ---------------- combine: out = x1 + w0*(moe0+moe1)[p0] + w1*(moe0+moe1)[p1]
__global__ __launch_bounds__(256) void combine_kernel(
    const float* __restrict__ x1, const _Float16* __restrict__ moe0,
    const _Float16* __restrict__ moe1,
    const float* __restrict__ topw, const int* __restrict__ posof, float* __restrict__ out)
{
  int t = blockIdx.x, tid = threadIdx.x;
  size_t o = (size_t)t*DD + tid*4;
  f4 xv = *(const f4*)(x1+o);
  int p0=posof[2*t], p1=posof[2*t+1];
  float w0=topw[2*t], w1=topw[2*t+1];
  h4v a0 = *(const h4v*)(moe0 + (size_t)p0*DD + tid*4);
  h4v b0 = *(const h4v*)(moe1 + (size_t)p0*DD + tid*4);
  h4v a1 = *(const h4v*)(moe0 + (size_t)p1*DD + tid*4);
  h4v b1 = *(const h4v*)(moe1 + (size_t)p1*DD + tid*4);
  f4 r;
  #pragma unroll
  for (int j=0;j<4;++j)
    r[j] = xv[j] + w0*((float)a0[j]+(float)b0[j]) + w1*((float)a1[j]+(float)b1[j]);
  *(f4*)(out+o) = r;
}

extern "C" void kernel_launch(void* const* d_in, const int* in_sizes, int n_in,
                              void* d_out, int out_size, void* d_ws, size_t ws_size,
                              hipStream_t stream)
{
  (void)in_sizes; (void)n_in; (void)out_size; (void)ws_size;
  const float* x     = (const float*)d_in[0];
  const float* ln1g  = (const float*)d_in[1];
  const float* ln1b  = (const float*)d_in[2];
  const float* wqkv  = (const float*)d_in[3];
  const float* bqkv  = (const float*)d_in[4];
  const float* wo    = (const float*)d_in[5];
  const float* bo    = (const float*)d_in[6];
  const float* ln2g  = (const float*)d_in[7];
  const float* ln2b  = (const float*)d_in[8];
  const float* gatew = (const float*)d_in[9];
  const float* gateb = (const float*)d_in[10];
  const float* W1    = (const float*)d_in[11];
  const float* b1    = (const float*)d_in[12];
  const float* W2    = (const float*)d_in[13];
  const float* b2    = (const float*)d_in[14];
  float* out = (float*)d_out;

  char* w = (char*)d_ws;
  // persistent converted weights
  _Float16* W1T    = (_Float16*)(w);                      // 67,108,864
  _Float16* W2T    = (_Float16*)(w + 67108864);           // 67,108,864
  _Float16* wqT_H  = (_Float16*)(w + 134217728);          //  6,291,456
  _Float16* wqT_L  = (_Float16*)(w + 140509184);          //  6,291,456
  _Float16* woT_H  = (_Float16*)(w + 146800640);          //  2,097,152
  _Float16* woT_L  = (_Float16*)(w + 148897792);          //  2,097,152
  // moe1 (FF2 split-K partial) aliases wqT/woT region (dead by FF2 time): 16,777,216
  _Float16* moe1   = (_Float16*)(w + 134217728);
  // R_big: h1 + qkv; h1 region later aliased by vt; whole region later hid
  char* rb = w + 150994944;                               // 67,108,864
  _Float16* h1H  = (_Float16*)(rb);
  _Float16* h1L  = (_Float16*)(rb + 8388608);
  _Float16* vtH  = (_Float16*)(rb);                       // alias h1 (dead after QKV)
  _Float16* vtL  = (_Float16*)(rb + 8388608);
  _Float16* qkvH = (_Float16*)(rb + 16777216);
  _Float16* qkvL = (_Float16*)(rb + 41943040);
  _Float16* hid  = (_Float16*)(rb);                       // alias all (after attn)
  // R_moe: o planes, later moe0
  char* rm = w + 218103808;                               // 16,777,216
  _Float16* oH   = (_Float16*)(rm);
  _Float16* oL   = (_Float16*)(rm + 8388608);
  _Float16* moe0 = (_Float16*)(rm);
  float* x1     = (float*)(w + 234881024);                // 16,777,216
  _Float16* h2h = (_Float16*)(w + 251658240);             //  8,388,608
  char* sm = w + 260046848;
  float* topw  = (float*)(sm);
  int*   topi  = (int*)(sm + 32768);
  int*   posof = (int*)(sm + 65536);
  int*   tokl  = (int*)(sm + 98304);
  int*   cnt   = (int*)(sm + 131072);
  int*   offs  = (int*)(sm + 131072 + 64);
  int*   cursor= (int*)(sm + 131072 + 128);
  int*   pref1 = (int*)(sm + 131072 + 192);
  int*   pref2 = (int*)(sm + 131072 + 256);

  // weight converts (transpose to [N][K], f16/split-f16), 64x64 tiles
  conv_t<1><<<dim3(48, 16, 1), 256, 0, stream>>>(wqkv, wqT_H, wqT_L, 1024, 3072);
  conv_t<1><<<dim3(16, 16, 1), 256, 0, stream>>>(wo,   woT_H, woT_L, 1024, 1024);
  conv_t<0><<<dim3(64, 16, 8), 256, 0, stream>>>(W1, W1T, nullptr, 1024, 4096);
  conv_t<0><<<dim3(16, 64, 8), 256, 0, stream>>>(W2, W2T, nullptr, 4096, 1024);

  ln_kernel<<<TT, 256, 0, stream>>>(x, ln1g, ln1b, h1H, h1L);
  gemm_split3<0><<<768, 256, 0, stream>>>(
      h1H, h1L, wqT_H, wqT_L, bqkv, qkvH, qkvL, nullptr, nullptr, 3072, 1024, 32);
  vt_kernel<<<dim3(32, 32), 256, 0, stream>>>(qkvH, qkvL, vtH, vtL);
  attn_kernel<<<dim3(SS/128, 2*NH), 256, 0, stream>>>(qkvH, qkvL, vtH, vtL, oH, oL);
  gemm_split3<1><<<256, 256, 0, stream>>>(
      oH, oL, woT_H, woT_L, bo, nullptr, nullptr, x1, x, 1024, 1024, 32);
  hipMemsetAsync(cnt, 0, 8*sizeof(int), stream);
  gate_kernel<<<TT/4, 256, 0, stream>>>(x1, ln2g, ln2b, gatew, gateb, h2h, topi, topw, cnt);
  scan_kernel<<<1, 32, 0, stream>>>(cnt, offs, cursor, pref1, pref2);
  scatter_kernel<<<TT/256, 256, 0, stream>>>(topi, offs, cursor, tokl, posof);
  gemm_ffn<1,1><<<1024, 256, 0, stream>>>(
      h2h, W1T, b1, hid, hid, tokl, offs, pref1, DFFC, 1024);
  gemm_ffn<0,2><<<1024, 256, 0, stream>>>(
      hid, W2T, b2, moe0, moe1, tokl, offs, pref2, DD, DFFC);
  combine_kernel<<<TT, 256, 0, stream>>>(x1, moe0, moe1, topw, posof, out);
}

// Round 16
// 719.620 us; speedup vs baseline: 1.0464x; 1.0464x over previous
//
#include <hip/hip_runtime.h>

#define TT 4096      // B*S tokens
#define SS 2048
#define DD 1024
#define NH 16
#define NE 8
#define DFFC 4096

typedef _Float16 h8  __attribute__((ext_vector_type(8)));
typedef _Float16 h4v __attribute__((ext_vector_type(4)));
typedef float    f4  __attribute__((ext_vector_type(4)));

typedef __attribute__((address_space(3))) void lds_void;
typedef __attribute__((address_space(1))) const void gbl_void;

__device__ __forceinline__ f4 mfma16(h8 a, h8 b, f4 c){
  return __builtin_amdgcn_mfma_f32_16x16x32_f16(a, b, c, 0, 0, 0);
}
__device__ __forceinline__ void fsplit(float x, _Float16& hi, _Float16& lo){
  _Float16 h = (_Float16)x; hi = h; lo = (_Float16)(x - (float)h);
}
// async global->LDS, 16B per lane. LDS dest must be linear (base + lane*16).
__device__ __forceinline__ void gll16(const void* g, void* l){
  __builtin_amdgcn_global_load_lds((gbl_void*)g, (lds_void*)l, 16, 0, 0);
}

// ---------------- transpose+convert: in f32 [K][N] -> out f16 [N][K] (split or single)
template<int SPLIT>
__global__ __launch_bounds__(256) void conv_t(
    const float* __restrict__ in, _Float16* __restrict__ oh, _Float16* __restrict__ ol,
    int K, int N)
{
  __shared__ float tile[64][65];
  const int n0 = blockIdx.x*64, k0 = blockIdx.y*64;
  const int tid = threadIdx.x;
  const float* inp = in + (size_t)blockIdx.z*K*N;
  #pragma unroll
  for (int p=0;p<4;++p){
    int row = p*16 + (tid>>4), col4 = (tid&15)*4;
    *(f4*)&tile[row][col4] = *(const f4*)(inp + (size_t)(k0+row)*N + n0 + col4);
  }
  __syncthreads();
  const size_t ob = (size_t)blockIdx.z*K*N;
  #pragma unroll
  for (int p=0;p<2;++p){
    int n = p*32 + (tid>>3), k8 = (tid&7)*8;
    h8 vh, vl;
    #pragma unroll
    for (int j=0;j<8;++j){
      float v = tile[k8+j][n];
      if constexpr (SPLIT){ _Float16 hi,lo; fsplit(v,hi,lo); vh[j]=hi; vl[j]=lo; }
      else vh[j] = (_Float16)v;
    }
    size_t o = ob + (size_t)(n0+n)*K + k0 + k8;
    *(h8*)(oh + o) = vh;
    if constexpr (SPLIT) *(h8*)(ol + o) = vl;
  }
}

// ---------------- LayerNorm (LN1): fp32 in -> split f16 planes
__global__ __launch_bounds__(256) void ln_kernel(
    const float* __restrict__ in, const float* __restrict__ g, const float* __restrict__ b,
    _Float16* __restrict__ outHi, _Float16* __restrict__ outLo)
{
  const int t = blockIdx.x, tid = threadIdx.x;
  f4 v = ((const f4*)(in + (size_t)t*DD))[tid];
  float s = v.x+v.y+v.z+v.w;
  float q = v.x*v.x+v.y*v.y+v.z*v.z+v.w*v.w;
  #pragma unroll
  for (int off=32; off; off>>=1){ s += __shfl_xor(s,off); q += __shfl_xor(q,off); }
  __shared__ float red[8];
  int wid = tid>>6, lane = tid&63;
  if (lane==0){ red[wid]=s; red[4+wid]=q; }
  __syncthreads();
  s = red[0]+red[1]+red[2]+red[3];
  q = red[4]+red[5]+red[6]+red[7];
  float mean = s * (1.0f/DD);
  float var  = q * (1.0f/DD) - mean*mean;
  float vv = var + 1e-5f;
  float r = rsqrtf(vv);
  r = r * (1.5f - 0.5f*vv*r*r);
  f4 gv = ((const f4*)g)[tid], bv = ((const f4*)b)[tid];
  #pragma unroll
  for (int j=0;j<4;++j){
    float y = (v[j]-mean)*r*gv[j] + bv[j];
    size_t o = (size_t)t*DD + tid*4 + j;
    _Float16 hi,lo; fsplit(y,hi,lo); outHi[o]=hi; outLo[o]=lo;
  }
}

// ---------------- split-precision GEMM (3-term), single-buffer 2-barrier loop (m97 style)
template<int MODE>
__global__ __launch_bounds__(256,3) void gemm_split3(
    const _Float16* __restrict__ Ah, const _Float16* __restrict__ Al,
    const _Float16* __restrict__ Bh, const _Float16* __restrict__ Bl,
    const float* __restrict__ bias,
    _Float16* __restrict__ Chi, _Float16* __restrict__ Clo,
    float* __restrict__ Cf, const float* __restrict__ resid,
    int N, int K, int GM)
{
  __shared__ __align__(16) char smem[32768];   // A 16K + B 16K, single buffer
  const int tid = threadIdx.x, lane = tid&63, wid = tid>>6;
  const int l15 = lane&15, l4 = lane>>4;
  const int bid = blockIdx.x;
  const int c = bid & 7, rr = bid >> 3, mpx = GM >> 3;
  const int tm = (c*mpx + (rr % mpx))*128, tn = (rr / mpx)*128;

  const _Float16* sA[4]; const _Float16* sB[4];
  #pragma unroll
  for (int i=0;i<4;++i){
    int row = i*32 + (tid>>3);
    int s = (tid&7) ^ (row&7);
    int plane = s>>2, koff = (s&3)*8;
    sA[i] = (plane ? Al : Ah) + (size_t)(tm+row)*K + koff;
    sB[i] = (plane ? Bl : Bh) + (size_t)(tn+row)*K + koff;
  }
  int offAh[4], offAl[4], offBh[4], offBl[4];
  #pragma unroll
  for (int m=0;m<4;++m){
    int rowA = (wid>>1)*64 + m*16 + l15;
    offAh[m] = rowA*64 + ((l4 ^ (rowA&7))<<3);
    offAl[m] = rowA*64 + (((4|l4) ^ (rowA&7))<<3);
    int rowB = (wid&1)*64 + m*16 + l15;
    offBh[m] = rowB*64 + ((l4 ^ (rowB&7))<<3);
    offBl[m] = rowB*64 + (((4|l4) ^ (rowB&7))<<3);
  }
  f4 acc[4][4] = {};
  const _Float16* As = (const _Float16*)(smem);
  const _Float16* Bs = (const _Float16*)(smem + 16384);
  for (int k0=0; k0<K; k0+=32){
    #pragma unroll
    for (int i=0;i<4;++i){
      int L = i*4096 + tid*16;
      gll16(sA[i]+k0, smem + L);
      gll16(sB[i]+k0, smem + 16384 + L);
    }
    __syncthreads();
    h8 ah[4], al[4], bh4[4], bl4[4];
    #pragma unroll
    for (int m=0;m<4;++m){ ah[m] = *(const h8*)&As[offAh[m]]; al[m] = *(const h8*)&As[offAl[m]]; }
    #pragma unroll
    for (int n=0;n<4;++n){ bh4[n] = *(const h8*)&Bs[offBh[n]]; bl4[n] = *(const h8*)&Bs[offBl[n]]; }
    #pragma unroll
    for (int n=0;n<4;++n)
      #pragma unroll
      for (int m=0;m<4;++m){
        acc[m][n] = mfma16(ah[m], bh4[n], acc[m][n]);
        acc[m][n] = mfma16(ah[m], bl4[n], acc[m][n]);
        acc[m][n] = mfma16(al[m], bh4[n], acc[m][n]);
      }
    __syncthreads();
  }
  const int wm = (wid>>1)*64, wn = (wid&1)*64;
  #pragma unroll
  for (int n=0;n<4;++n){
    int col = tn + wn + n*16 + l15;
    float bv = bias[col];
    #pragma unroll
    for (int m=0;m<4;++m)
      #pragma unroll
      for (int r=0;r<4;++r){
        int rowg = tm + wm + m*16 + l4*4 + r;
        float vv = acc[m][n][r] + bv;
        size_t co = (size_t)rowg*N + col;
        if constexpr (MODE==0){ _Float16 hi,lo; fsplit(vv,hi,lo); Chi[co]=hi; Clo[co]=lo; }
        else { Cf[co] = vv + resid[co]; }
      }
  }
}

// ---------------- V pre-transpose: qkv planes -> vt [bh][64 d][2048 tokens]
__global__ __launch_bounds__(256) void vt_kernel(
    const _Float16* __restrict__ qkvH, const _Float16* __restrict__ qkvL,
    _Float16* __restrict__ vtH, _Float16* __restrict__ vtL)
{
  __shared__ _Float16 TH[64*72], TL[64*72];
  const int tid = threadIdx.x;
  const int tt = blockIdx.x*64;
  const int bh = blockIdx.y;
  const int b = bh>>4, h = bh&15;
  const size_t t0 = (size_t)b*SS;
  #pragma unroll
  for (int p=0;p<2;++p){
    int t = p*32 + (tid>>3), d0 = (tid&7)*8;
    size_t g = (t0 + tt + t)*(size_t)3072 + 2048 + h*64 + d0;
    h8 vh = *(const h8*)(qkvH+g), vl = *(const h8*)(qkvL+g);
    int cp = ((t>>3) ^ (tid&7)) & 7;        // swizzled t-chunk
    int base = cp*8 + (t&7);
    #pragma unroll
    for (int j=0;j<8;++j){ TH[(d0+j)*72 + base] = vh[j]; TL[(d0+j)*72 + base] = vl[j]; }
  }
  __syncthreads();
  int d = tid>>2, seg = tid&3;
  size_t ob = ((size_t)bh*64 + d)*2048 + tt;
  #pragma unroll
  for (int jj=0;jj<2;++jj){
    int cch = jj*4 + seg, cp = (cch ^ (d>>3)) & 7;
    h8 vh = *(const h8*)&TH[d*72 + cp*8];
    h8 vl = *(const h8*)&TL[d*72 + cp*8];
    *(h8*)(vtH + ob + cch*8) = vh;
    *(h8*)(vtL + ob + cch*8) = vl;
  }
}

// ---------------- flash attention, split-f16, swapped QK^T + fixed-shift softmax
__global__ __launch_bounds__(256,3) void attn_kernel(
    const _Float16* __restrict__ qkvH, const _Float16* __restrict__ qkvL,
    const _Float16* __restrict__ vtH, const _Float16* __restrict__ vtL,
    _Float16* __restrict__ oH, _Float16* __restrict__ oL)
{
  __shared__ __align__(16) _Float16 KsH[64*64], KsL[64*64], VsH[64*64], VsL[64*64];
  __shared__ __align__(16) _Float16 Plds[10240];  // 4 waves x (32q x 80B hi + 32q x 80B lo)
  const int tid = threadIdx.x, lane = tid & 63, wid = tid >> 6;
  const int l15 = lane & 15, l4 = lane >> 4;
  const int qt = blockIdx.x, bh = blockIdx.y;
  const int b = bh >> 4, h = bh & 15;
  const size_t t0 = (size_t)b * SS;
  const int qbase = qt*128 + wid*32;

  const int srow = tid>>3;
  const int ss = (tid&7) ^ (srow&7);
  const _Float16* kH = qkvH + (t0 + srow)*(size_t)3072 + 1024 + h*64 + ss*8;
  const _Float16* kL = qkvL + (t0 + srow)*(size_t)3072 + 1024 + h*64 + ss*8;
  const _Float16* vH = vtH + ((size_t)bh*64 + srow)*2048 + ss*8;
  const _Float16* vL = vtL + ((size_t)bh*64 + srow)*2048 + ss*8;
  const int ldsL0 = tid*16;

  int offF[4][2];
  #pragma unroll
  for (int n=0;n<4;++n)
    #pragma unroll
    for (int ks=0;ks<2;++ks){
      int row = n*16 + l15;
      offF[n][ks] = row*64 + (((ks*4 + l4) ^ (row&7))<<3);
    }
  int pq[2], prb[2];
  #pragma unroll
  for (int m=0;m<2;++m){
    int q = m*16 + l15;
    pq[m]  = wid*5120 + q*80;
    prb[m] = pq[m] + l4*16;
  }

  h8 qh[2][2], ql[2][2];
  #pragma unroll
  for (int m=0;m<2;++m)
    #pragma unroll
    for (int ks=0;ks<2;++ks){
      size_t go = (t0 + qbase + m*16 + l15)*(size_t)3072 + h*64 + ks*32 + l4*8;
      qh[m][ks] = *(const h8*)(qkvH + go);
      ql[m][ks] = *(const h8*)(qkvL + go);
    }

  f4 oacc[2][4] = {};
  float psum[2] = {0.f, 0.f};

  for (int kv=0; kv<SS; kv+=64){
    #pragma unroll
    for (int cc=0; cc<2; ++cc){
      size_t kgo = (size_t)(kv + cc*32)*3072;
      size_t vgo = (size_t)kv + (size_t)cc*32*2048;
      int L = cc*4096 + ldsL0;
      gll16(kH + kgo, (char*)KsH + L);
      gll16(kL + kgo, (char*)KsL + L);
      gll16(vH + vgo, (char*)VsH + L);
      gll16(vL + vgo, (char*)VsL + L);
    }
    __syncthreads();

    #pragma unroll
    for (int half=0; half<2; ++half){
      f4 s[2][2] = {};
      __builtin_amdgcn_s_setprio(1);
      #pragma unroll
      for (int n2=0;n2<2;++n2){
        int nn = half*2 + n2;
        #pragma unroll
        for (int ks=0;ks<2;++ks){
          h8 kh = *(const h8*)&KsH[offF[nn][ks]];
          h8 kl = *(const h8*)&KsL[offF[nn][ks]];
          s[0][n2] = mfma16(kh, qh[0][ks], s[0][n2]);
          s[0][n2] = mfma16(kl, qh[0][ks], s[0][n2]);
          s[0][n2] = mfma16(kh, ql[0][ks], s[0][n2]);
          s[1][n2] = mfma16(kh, qh[1][ks], s[1][n2]);
          s[1][n2] = mfma16(kl, qh[1][ks], s[1][n2]);
          s[1][n2] = mfma16(kh, ql[1][ks], s[1][n2]);
        }
      }
      __builtin_amdgcn_s_setprio(0);
      #pragma unroll
      for (int m=0;m<2;++m){
        #pragma unroll
        for (int n2=0;n2<2;++n2){
          f4 sv = s[m][n2];
          float p0 = __expf(fmaf(sv.x, 0.125f, -8.0f));
          float p1 = __expf(fmaf(sv.y, 0.125f, -8.0f));
          float p2 = __expf(fmaf(sv.z, 0.125f, -8.0f));
          float p3 = __expf(fmaf(sv.w, 0.125f, -8.0f));
          psum[m] += (p0+p1)+(p2+p3);
          h4v hv, lv; _Float16 hh, ll;
          fsplit(p0,hh,ll); hv[0]=hh; lv[0]=ll;
          fsplit(p1,hh,ll); hv[1]=hh; lv[1]=ll;
          fsplit(p2,hh,ll); hv[2]=hh; lv[2]=ll;
          fsplit(p3,hh,ll); hv[3]=hh; lv[3]=ll;
          int wb = pq[m] + n2*32 + l4*8;
          *(h4v*)((char*)Plds + wb) = hv;
          *(h4v*)((char*)Plds + 2560 + wb) = lv;
        }
      }
      __builtin_amdgcn_s_setprio(1);
      h8 paH0 = *(const h8*)((char*)Plds + prb[0]);
      h8 paL0 = *(const h8*)((char*)Plds + 2560 + prb[0]);
      h8 paH1 = *(const h8*)((char*)Plds + prb[1]);
      h8 paL1 = *(const h8*)((char*)Plds + 2560 + prb[1]);
      #pragma unroll
      for (int nd=0;nd<4;++nd){
        h8 vh = *(const h8*)&VsH[offF[nd][half]];
        h8 vl = *(const h8*)&VsL[offF[nd][half]];
        oacc[0][nd] = mfma16(paH0, vh, oacc[0][nd]);
        oacc[0][nd] = mfma16(paH0, vl, oacc[0][nd]);
        oacc[0][nd] = mfma16(paL0, vh, oacc[0][nd]);
        oacc[1][nd] = mfma16(paH1, vh, oacc[1][nd]);
        oacc[1][nd] = mfma16(paH1, vl, oacc[1][nd]);
        oacc[1][nd] = mfma16(paL1, vh, oacc[1][nd]);
      }
      __builtin_amdgcn_s_setprio(0);
    }
    __syncthreads();
  }

  #pragma unroll
  for (int m=0;m<2;++m){
    float ls = psum[m];
    ls += __shfl_xor(ls, 16);
    ls += __shfl_xor(ls, 32);
    #pragma unroll
    for (int r=0;r<4;++r){
      int srcl = l4*4 + r;
      float lq = __uint_as_float(
          (unsigned)__builtin_amdgcn_ds_bpermute(srcl*4, (int)__float_as_uint(ls)));
      float linv = 1.0f / lq;
      #pragma unroll
      for (int nd=0;nd<4;++nd){
        float vv = oacc[m][nd][r] * linv;
        size_t go = (t0 + qbase + m*16 + l4*4 + r)*(size_t)DD + h*64 + nd*16 + l15;
        _Float16 hi, lo; fsplit(vv, hi, lo);
        oH[go] = hi; oL[go] = lo;
      }
    }
  }
}

// ---------------- fused LN2 + gate: x1 fp32 -> h2h f16 plane + top-2 routing.
__global__ __launch_bounds__(256) void gate_kernel(
    const float* __restrict__ x1, const float* __restrict__ g, const float* __restrict__ bb,
    const float* __restrict__ gw, const float* __restrict__ gb,
    _Float16* __restrict__ h2h,
    int* __restrict__ topi, float* __restrict__ topw, int* __restrict__ cnt)
{
  const int t = blockIdx.x*4 + (threadIdx.x>>6), lane = threadIdx.x & 63;
  f4 xv[4];
  float s=0.f, q=0.f;
  #pragma unroll
  for (int i=0;i<4;++i){
    xv[i] = ((const f4*)(x1 + (size_t)t*DD))[lane + i*64];
    #pragma unroll
    for (int j=0;j<4;++j){ s += xv[i][j]; q += xv[i][j]*xv[i][j]; }
  }
  #pragma unroll
  for (int off=32; off; off>>=1){ s += __shfl_xor(s,off); q += __shfl_xor(q,off); }
  float mean = s*(1.f/DD), var = q*(1.f/DD)-mean*mean, vv = var+1e-5f;
  float r = rsqrtf(vv); r = r*(1.5f-0.5f*vv*r*r);
  float acc[8] = {0,0,0,0,0,0,0,0};
  #pragma unroll
  for (int i=0;i<4;++i){
    f4 gv = ((const f4*)g)[lane+i*64], bv = ((const f4*)bb)[lane+i*64];
    h4v hv4;
    #pragma unroll
    for (int j=0;j<4;++j){
      int d = (lane+i*64)*4 + j;
      float hv = (xv[i][j]-mean)*r*gv[j] + bv[j];
      hv4[j] = (_Float16)hv;
      const f4* gp = (const f4*)(gw + (size_t)d*8);
      f4 g0 = gp[0], g1 = gp[1];
      acc[0]+=hv*g0.x; acc[1]+=hv*g0.y; acc[2]+=hv*g0.z; acc[3]+=hv*g0.w;
      acc[4]+=hv*g1.x; acc[5]+=hv*g1.y; acc[6]+=hv*g1.z; acc[7]+=hv*g1.w;
    }
    *(h4v*)(h2h + (size_t)t*DD + (lane+i*64)*4) = hv4;   // fused ln2 f16 output
  }
  #pragma unroll
  for (int e=0;e<8;++e)
    #pragma unroll
    for (int off=32;off;off>>=1) acc[e]+=__shfl_xor(acc[e],off);
  if (lane==0){
    float lg[8];
    #pragma unroll
    for (int e=0;e<8;++e) lg[e]=acc[e]+gb[e];
    int i0=0; float v0=lg[0];
    #pragma unroll
    for (int e=1;e<8;++e) if (lg[e]>v0){ v0=lg[e]; i0=e; }
    int i1=-1; float v1=-1e30f;
    #pragma unroll
    for (int e=0;e<8;++e) if (e!=i0 && lg[e]>v1){ v1=lg[e]; i1=e; }
    float w0 = 1.f/(1.f+__expf(v1-v0));
    topi[2*t]=i0; topi[2*t+1]=i1;
    topw[2*t]=w0; topw[2*t+1]=1.f-w0;
    atomicAdd(&cnt[i0],1); atomicAdd(&cnt[i1],1);
  }
}

__global__ void scan_kernel(const int* __restrict__ cnt, int* __restrict__ offs,
                            int* __restrict__ cursor, int* __restrict__ pref1,
                            int* __restrict__ pref2){
  if (threadIdx.x==0){
    int s=0, t1=0, t2=0;
    for (int e=0;e<8;++e){
      offs[e]=s; s+=cnt[e];
      int mt = (cnt[e]+127)>>7;
      pref1[e]=t1; t1 += mt*(DFFC/128);
      pref2[e]=t2; t2 += mt*(DD/128)*2;   // x2: split-K halves
    }
    offs[8]=s; pref1[8]=t1; pref2[8]=t2;
  }
  if (threadIdx.x<8) cursor[threadIdx.x]=0;
}

__global__ __launch_bounds__(256) void scatter_kernel(
    const int* __restrict__ topi, const int* __restrict__ offs, int* __restrict__ cursor,
    int* __restrict__ tokl, int* __restrict__ posof)
{
  int t = blockIdx.x*256 + threadIdx.x;
  #pragma unroll
  for (int k=0;k<2;++k){
    int e = topi[2*t+k];
    int p = atomicAdd(&cursor[e],1);
    int idx = offs[e]+p;
    tokl[idx]=t; posof[2*t+k]=idx;
  }
}

// ---------------- grouped expert GEMM, f16 x f16, BK=64, single-buffer, tile scheduler.
// (R14-verified structure: stage -> sync -> compute -> sync, 4 blocks/CU)
template<int GATHER, int KH>
__global__ __launch_bounds__(256,4) void gemm_ffn(
    const _Float16* __restrict__ A, const _Float16* __restrict__ Bw,
    const float* __restrict__ bias, _Float16* __restrict__ C0, _Float16* __restrict__ C1,
    const int* __restrict__ tok, const int* __restrict__ offs,
    const int* __restrict__ pref, int N, int K)
{
  __shared__ __align__(16) char smem[32768];
  const int tid = threadIdx.x, lane = tid&63, wid = tid>>6;
  const int l15 = lane&15, l4 = lane>>4;
  const int wm = (wid>>1)*64, wn = (wid&1)*64;
  const int tot = pref[8];
  const int nt = N>>7;
  const int KSEG = K/KH;

  int offA[4][2], offB[4][2];
  #pragma unroll
  for (int m=0;m<4;++m)
    #pragma unroll
    for (int ks=0;ks<2;++ks){
      int rowA = wm + m*16 + l15;
      offA[m][ks] = rowA*64 + (((ks*4+l4) ^ (rowA&7))<<3);
      int rowB = wn + m*16 + l15;
      offB[m][ks] = rowB*64 + (((ks*4+l4) ^ (rowB&7))<<3);
    }

  // XCD-chunked bijective swizzle (gridDim.x % 8 == 0)
  const int cpx = gridDim.x >> 3;
  const int bswz = (blockIdx.x & 7)*cpx + (blockIdx.x >> 3);
  for (int idx = bswz; idx < tot; idx += gridDim.x){
    int e = 0;
    #pragma unroll
    for (int k=1;k<8;++k) if (pref[k] <= idx) e = k;
    const int off = offs[e], Me = offs[e+1]-off;
    const int mt = (Me+127)>>7;
    int local = idx - pref[e];
    int kh = 0;
    if constexpr (KH==2){ int per = mt*nt; kh = (local >= per); local -= kh*per; }
    const int ni = local / mt, mi = local - ni*mt;
    const int tm = mi*128, tn = ni*128;
    const int kb = kh*KSEG;
    const _Float16* Bp = Bw + (size_t)e*N*K + (size_t)tn*K;
    const float* biasp = bias + (size_t)e*N;

    const _Float16* sA[4]; const _Float16* sB[4];
    #pragma unroll
    for (int i=0;i<4;++i){
      int row = i*32 + (tid>>3);
      int s = (tid&7) ^ (row&7);
      int lr = min(tm+row, Me-1);
      size_t ar = GATHER ? (size_t)tok[off+lr] : (size_t)(off+lr);
      sA[i] = A + ar*K + s*8 + kb;
      sB[i] = Bp + (size_t)row*K + s*8 + kb;
    }
    f4 acc[4][4] = {};
    const _Float16* As = (const _Float16*)(smem);
    const _Float16* Bs = (const _Float16*)(smem + 16384);
    for (int k0=0; k0<KSEG; k0+=64){
      #pragma unroll
      for (int i=0;i<4;++i){
        int L = i*4096 + tid*16;
        gll16(sA[i]+k0, smem + L);
        gll16(sB[i]+k0, smem + 16384 + L);
      }
      __syncthreads();
      #pragma unroll
      for (int ks=0;ks<2;++ks){
        h8 av[4], bv[4];
        #pragma unroll
        for (int m=0;m<4;++m) av[m] = *(const h8*)&As[offA[m][ks]];
        #pragma unroll
        for (int n=0;n<4;++n) bv[n] = *(const h8*)&Bs[offB[n][ks]];
        #pragma unroll
        for (int n=0;n<4;++n)
          #pragma unroll
          for (int m=0;m<4;++m)
            acc[m][n] = mfma16(av[m], bv[n], acc[m][n]);
      }
      __syncthreads();
    }
    // epilogue: LDS bounce, two 64-col passes, coalesced 16B stores
    _Float16* Cp = (KH==2 && kh==1) ? C1 : C0;
    _Float16* Cs = (_Float16*)smem;
    float bvv[4];
    #pragma unroll
    for (int n=0;n<4;++n) bvv[n] = (KH==2 && kh==1) ? 0.f : biasp[tn + wn + n*16 + l15];
    #pragma unroll
    for (int p=0;p<2;++p){
      if ((wid&1)==p){
        #pragma unroll
        for (int n=0;n<4;++n)
          #pragma unroll
          for (int m=0;m<4;++m)
            #pragma unroll
            for (int r=0;r<4;++r){
              int row = wm + m*16 + l4*4 + r;
              float vv = acc[m][n][r] + bvv[n];
              if constexpr (GATHER) vv = fmaxf(vv, 0.f);
              Cs[row*72 + n*16 + l15] = (_Float16)vv;
            }
      }
      __syncthreads();
      int row = tid>>1, seg = tid&1;
      if (tm+row < Me){
        size_t gb = (size_t)(off+tm+row)*N + tn + p*64 + seg*32;
        #pragma unroll
        for (int j=0;j<4;++j)
          *(h8*)(Cp + gb + j*8) = *(const h8*)&Cs[row*72 + seg*32 + j*8];
      }
      __syncthreads();
    }
  }
}

// ---------------- combine: out = x1 + w0*(moe0+moe1)[p0] + w1*(moe0+moe1)[p1]
__global__ __launch_bounds__(256) void combine_kernel(
    const float* __restrict__ x1, const _Float16* __restrict__ moe0,
    const _Float16* __restrict__ moe1,
    const float* __restrict__ topw, const int* __restrict__ posof, float* __restrict__ out)
{
  int t = blockIdx.x, tid = threadIdx.x;
  size_t o = (size_t)t*DD + tid*4;
  f4 xv = *(const f4*)(x1+o);
  int p0=posof[2*t], p1=posof[2*t+1];
  float w0=topw[2*t], w1=topw[2*t+1];
  h4v a0 = *(const h4v*)(moe0 + (size_t)p0*DD + tid*4);
  h4v b0 = *(const h4v*)(moe1 + (size_t)p0*DD + tid*4);
  h4v a1 = *(const h4v*)(moe0 + (size_t)p1*DD + tid*4);
  h4v b1 = *(const h4v*)(moe1 + (size_t)p1*DD + tid*4);
  f4 r;
  #pragma unroll
  for (int j=0;j<4;++j)
    r[j] = xv[j] + w0*((float)a0[j]+(float)b0[j]) + w1*((float)a1[j]+(float)b1[j]);
  *(f4*)(out+o) = r;
}

extern "C" void kernel_launch(void* const* d_in, const int* in_sizes, int n_in,
                              void* d_out, int out_size, void* d_ws, size_t ws_size,
                              hipStream_t stream)
{
  (void)in_sizes; (void)n_in; (void)out_size; (void)ws_size;
  const float* x     = (const float*)d_in[0];
  const float* ln1g  = (const float*)d_in[1];
  const float* ln1b  = (const float*)d_in[2];
  const float* wqkv  = (const float*)d_in[3];
  const float* bqkv  = (const float*)d_in[4];
  const float* wo    = (const float*)d_in[5];
  const float* bo    = (const float*)d_in[6];
  const float* ln2g  = (const float*)d_in[7];
  const float* ln2b  = (const float*)d_in[8];
  const float* gatew = (const float*)d_in[9];
  const float* gateb = (const float*)d_in[10];
  const float* W1    = (const float*)d_in[11];
  const float* b1    = (const float*)d_in[12];
  const float* W2    = (const float*)d_in[13];
  const float* b2    = (const float*)d_in[14];
  float* out = (float*)d_out;

  char* w = (char*)d_ws;
  // persistent converted weights
  _Float16* W1T    = (_Float16*)(w);                      // 67,108,864
  _Float16* W2T    = (_Float16*)(w + 67108864);           // 67,108,864
  _Float16* wqT_H  = (_Float16*)(w + 134217728);          //  6,291,456
  _Float16* wqT_L  = (_Float16*)(w + 140509184);          //  6,291,456
  _Float16* woT_H  = (_Float16*)(w + 146800640);          //  2,097,152
  _Float16* woT_L  = (_Float16*)(w + 148897792);          //  2,097,152
  // moe1 (FF2 split-K partial) aliases wqT/woT region (dead by FF2 time): 16,777,216
  _Float16* moe1   = (_Float16*)(w + 134217728);
  // R_big: h1 + qkv; h1 region later aliased by vt; whole region later hid
  char* rb = w + 150994944;                               // 67,108,864
  _Float16* h1H  = (_Float16*)(rb);
  _Float16* h1L  = (_Float16*)(rb + 8388608);
  _Float16* vtH  = (_Float16*)(rb);                       // alias h1 (dead after QKV)
  _Float16* vtL  = (_Float16*)(rb + 8388608);
  _Float16* qkvH = (_Float16*)(rb + 16777216);
  _Float16* qkvL = (_Float16*)(rb + 41943040);
  _Float16* hid  = (_Float16*)(rb);                       // alias all (after attn)
  // R_moe: o planes, later moe0
  char* rm = w + 218103808;                               // 16,777,216
  _Float16* oH   = (_Float16*)(rm);
  _Float16* oL   = (_Float16*)(rm + 8388608);
  _Float16* moe0 = (_Float16*)(rm);
  float* x1     = (float*)(w + 234881024);                // 16,777,216
  _Float16* h2h = (_Float16*)(w + 251658240);             //  8,388,608
  char* sm = w + 260046848;
  float* topw  = (float*)(sm);
  int*   topi  = (int*)(sm + 32768);
  int*   posof = (int*)(sm + 65536);
  int*   tokl  = (int*)(sm + 98304);
  int*   cnt   = (int*)(sm + 131072);
  int*   offs  = (int*)(sm + 131072 + 64);
  int*   cursor= (int*)(sm + 131072 + 128);
  int*   pref1 = (int*)(sm + 131072 + 192);
  int*   pref2 = (int*)(sm + 131072 + 256);

  // weight converts (transpose to [N][K], f16/split-f16), 64x64 tiles
  conv_t<1><<<dim3(48, 16, 1), 256, 0, stream>>>(wqkv, wqT_H, wqT_L, 1024, 3072);
  conv_t<1><<<dim3(16, 16, 1), 256, 0, stream>>>(wo,   woT_H, woT_L, 1024, 1024);
  conv_t<0><<<dim3(64, 16, 8), 256, 0, stream>>>(W1, W1T, nullptr, 1024, 4096);
  conv_t<0><<<dim3(16, 64, 8), 256, 0, stream>>>(W2, W2T, nullptr, 4096, 1024);

  ln_kernel<<<TT, 256, 0, stream>>>(x, ln1g, ln1b, h1H, h1L);
  gemm_split3<0><<<768, 256, 0, stream>>>(
      h1H, h1L, wqT_H, wqT_L, bqkv, qkvH, qkvL, nullptr, nullptr, 3072, 1024, 32);
  vt_kernel<<<dim3(32, 32), 256, 0, stream>>>(qkvH, qkvL, vtH, vtL);
  attn_kernel<<<dim3(SS/128, 2*NH), 256, 0, stream>>>(qkvH, qkvL, vtH, vtL, oH, oL);
  gemm_split3<1><<<256, 256, 0, stream>>>(
      oH, oL, woT_H, woT_L, bo, nullptr, nullptr, x1, x, 1024, 1024, 32);
  hipMemsetAsync(cnt, 0, 8*sizeof(int), stream);
  gate_kernel<<<TT/4, 256, 0, stream>>>(x1, ln2g, ln2b, gatew, gateb, h2h, topi, topw, cnt);
  scan_kernel<<<1, 32, 0, stream>>>(cnt, offs, cursor, pref1, pref2);
  scatter_kernel<<<TT/256, 256, 0, stream>>>(topi, offs, cursor, tokl, posof);
  gemm_ffn<1,1><<<1024, 256, 0, stream>>>(
      h2h, W1T, b1, hid, hid, tokl, offs, pref1, DFFC, 1024);
  gemm_ffn<0,2><<<1024, 256, 0, stream>>>(
      hid, W2T, b2, moe0, moe1, tokl, offs, pref2, DD, DFFC);
  combine_kernel<<<TT, 256, 0, stream>>>(x1, moe0, moe1, topw, posof, out);
}